// Round 13
// baseline (1408.870 us; speedup 1.0000x reference)
//
#include <hip/hip_runtime.h>
#include <cstdint>
#include <math.h>

#define NPTS 2048
#define NBATCH 16
#define KNBR 20

// ws layout (float offsets)
#define OFF_YT   0u         // [B*N][64]: y(32) | t1c(32)   2097152
#define OFF_W1AF 2097152u   // [32][64]
#define OFF_W1BF 2099200u   // [32][64]
#define OFF_B1F  2101248u   // [32]
#define OFF_B2F  2101280u   // [32] (folded bias; consecutive pairs = pair layout)
#define OFF_W2P  2101312u   // [16][32][2] paired rows of folded W2
#define OFF_W3P  2103360u   // [32][32][2] paired rows of W3
#define OFF_IDX  2105408u   // int [B*N][20]

// ---------------- fold BN into weights (+ pair layouts for pk_fma) ----------------
__global__ void fold_kernel(const float* __restrict__ W1, const float* __restrict__ g1,
                            const float* __restrict__ b1, const float* __restrict__ m1,
                            const float* __restrict__ v1, const float* __restrict__ W2,
                            const float* __restrict__ g2, const float* __restrict__ b2,
                            const float* __restrict__ m2, const float* __restrict__ v2,
                            const float* __restrict__ W3,
                            float* __restrict__ W1AF, float* __restrict__ W1BF,
                            float* __restrict__ B1F, float* __restrict__ B2F,
                            float* __restrict__ W2P, float* __restrict__ W3P) {
  const int o = threadIdx.x;
  if (o < 32) {
    const float s1 = g1[o] / sqrtf(v1[o] + 1e-5f);
    const float s2 = g2[o] / sqrtf(v2[o] + 1e-5f);
    B1F[o] = b1[o] - m1[o] * s1;
    B2F[o] = b2[o] - m2[o] * s2;
    for (int c = 0; c < 64; ++c) {
      W1AF[o * 64 + c] = W1[o * 128 + c] * s1;
      W1BF[o * 64 + c] = W1[o * 128 + 64 + c] * s1;
    }
    // paired W2: W2P[((o>>1)*32 + c)*2 + (o&1)] = W2F[o][c]
    for (int c = 0; c < 32; ++c)
      W2P[(((o >> 1) << 5) + c) * 2 + (o & 1)] = W2[o * 32 + c] * s2;
  }
  if (o < 64) {
    // paired W3 (no BN): W3P[((o>>1)*32 + c)*2 + (o&1)] = W3[o][c]
    for (int c = 0; c < 32; ++c)
      W3P[(((o >> 1) << 5) + c) * 2 + (o & 1)] = W3[o * 32 + c];
  }
}

// ---------------- per-point precompute: y = W1a@xf, t1c = B1 + W1b@xf - y ----------------
__global__ __launch_bounds__(256) void pre_kernel(const float* __restrict__ xf,
                                                  const float* __restrict__ W1AF,
                                                  const float* __restrict__ W1BF,
                                                  const float* __restrict__ B1F,
                                                  float* __restrict__ yt) {
  const int p = blockIdx.x * 256 + threadIdx.x;  // 0..32767
  const int b = p >> 11, n = p & 2047;
  const float* src = xf + (size_t)b * 64 * NPTS + n;
  float cen[64];
#pragma unroll
  for (int c = 0; c < 64; ++c) cen[c] = src[(size_t)c * NPTS];
  float y[32], t1[32];
#pragma unroll
  for (int o = 0; o < 32; ++o) {
    float a = 0.f;
    float bb = B1F[o];
#pragma unroll
    for (int c = 0; c < 64; ++c) {
      a = fmaf(W1AF[o * 64 + c], cen[c], a);
      bb = fmaf(W1BF[o * 64 + c], cen[c], bb);
    }
    y[o] = a;
    t1[o] = bb - a;
  }
  float* dst = yt + (size_t)p * 64;
#pragma unroll
  for (int o = 0; o < 32; o += 4) {
    *(float4*)(dst + o) = make_float4(y[o], y[o + 1], y[o + 2], y[o + 3]);
    *(float4*)(dst + 32 + o) = make_float4(t1[o], t1[o + 1], t1[o + 2], t1[o + 3]);
  }
}

// ---------------- KNN: round-1 semantics, 8 slices x 64 queries, 512 threads ----------------
// Phase A: per-(query,slice) top-20 VALUES via branchless max/min ladder (256 cands).
// Rescan: collect indices with pd >= T ascending (cap 20).
// Phase B: merge 8x20 -> top-20; slices contiguous + ascending rescan => candidates
//          inserted in ascending global index with strict '>' => top_k tie-break.
__device__ __forceinline__ float pd_of(const float4 qp, const float nqxx, const float4 c) {
  const float dot = __fadd_rn(__fadd_rn(__fmul_rn(qp.x, c.x), __fmul_rn(qp.y, c.y)),
                              __fmul_rn(qp.z, c.z));
  return __fsub_rn(__fadd_rn(nqxx, __fmul_rn(2.0f, dot)), c.w);
}

__global__ __launch_bounds__(512, 4) void knn_kernel(const float* __restrict__ xyz,
                                                     int* __restrict__ knn_out) {
  __shared__ float4 spt[NPTS];        // 32 KB
  __shared__ int qlist[512 * KNBR];   // 40 KB
  const int b = blockIdx.x >> 5;
  const int qbase = (blockIdx.x & 31) << 6;
  const int tid = threadIdx.x;
  const float* src = xyz + (size_t)b * 3 * NPTS;
  for (int i = tid; i < NPTS; i += 512) {
    const float x = src[i], y = src[NPTS + i], z = src[2 * NPTS + i];
    const float xx = __fadd_rn(__fadd_rn(__fmul_rn(x, x), __fmul_rn(y, y)), __fmul_rn(z, z));
    spt[i] = make_float4(x, y, z, xx);
  }
  __syncthreads();

  const int q = qbase + (tid & 63);
  const int slice = tid >> 6;              // 0..7
  const float4 qp = spt[q];
  const float nqxx = -qp.w;
  const int j0 = slice << 8, j1 = j0 + 256;

  float arr[KNBR];
#pragma unroll
  for (int s = 0; s < KNBR; ++s) arr[s] = -INFINITY;
  for (int j = j0; j < j1; ++j) {
    float v = pd_of(qp, nqxx, spt[j]);
#pragma unroll
    for (int s = 0; s < KNBR; ++s) {  // branchless insert (values only)
      const float hi = fmaxf(arr[s], v);
      v = fminf(arr[s], v);
      arr[s] = hi;
    }
  }
  const float T = arr[KNBR - 1];
  int cnt = 0;
  int* myq = qlist + tid * KNBR;
  for (int j = j0; j < j1; ++j) {
    const float pd = pd_of(qp, nqxx, spt[j]);
    if (pd >= T && cnt < KNBR) { myq[cnt] = j; ++cnt; }
  }
  __syncthreads();

  if (tid < 64) {
    float bpd[KNBR];
    int bidx[KNBR];
#pragma unroll
    for (int s = 0; s < KNBR; ++s) { bpd[s] = -INFINITY; bidx[s] = 0; }
    const float4 qp2 = spt[qbase + tid];
    const float nq2 = -qp2.w;
    for (int s2 = 0; s2 < 8; ++s2) {
      for (int jj = 0; jj < KNBR; ++jj) {
        const int id = qlist[((s2 << 6) | tid) * KNBR + jj];
        const float v = pd_of(qp2, nq2, spt[id]);
        if (v > bpd[KNBR - 1]) {
#pragma unroll
          for (int s = KNBR - 1; s >= 1; --s) {
            const bool c1 = v > bpd[s - 1];
            const float pj = c1 ? bpd[s - 1] : v;
            const int ij = c1 ? bidx[s - 1] : id;
            if (v > bpd[s]) { bpd[s] = pj; bidx[s] = ij; }
          }
          if (v > bpd[0]) { bpd[0] = v; bidx[0] = id; }
        }
      }
    }
    int* dst = knn_out + ((size_t)(b * NPTS + qbase + tid)) * KNBR;
#pragma unroll
    for (int s = 0; s < KNBR; ++s) dst[s] = bidx[s];
  }
}

// ---------------- fused MLP + max-pool + shuffle-write ----------------
// thread = (point, k-quarter, o-half): 8 threads/point -> 4096 waves (4/SIMD).
// Layer1 = y[nb] + t1c (precomputed); layers 2/3 via paired float2 accs (pk_fma).
__global__ __launch_bounds__(256, 4) void mlp_kernel(const float* __restrict__ ws,
                                                     const int* __restrict__ knn,
                                                     float* __restrict__ out) {
  const int t = blockIdx.x * 256 + threadIdx.x;
  const int p = t >> 3;          // point id 0..32767
  const int kq = (t >> 1) & 3;   // k-quarter
  const int oh = t & 1;          // output half (o in [oh*32, oh*32+32))
  const int b = p >> 11;
  const int n = p & 2047;
  const float* __restrict__ yt = ws + OFF_YT;
  const float* __restrict__ W2P = ws + OFF_W2P;
  const float* __restrict__ W3P = ws + OFF_W3P;
  const float* __restrict__ B2F = ws + OFF_B2F;
  const float* __restrict__ ybase = yt + ((size_t)(b << 11)) * 64;

  float t1c[32];
  {
    const float* tp = yt + (size_t)p * 64 + 32;
#pragma unroll
    for (int o = 0; o < 32; o += 4) {
      const float4 v = *(const float4*)(tp + o);
      t1c[o] = v.x; t1c[o + 1] = v.y; t1c[o + 2] = v.z; t1c[o + 3] = v.w;
    }
  }
  float2 hm2[16];
#pragma unroll
  for (int j = 0; j < 16; ++j) hm2[j] = make_float2(-INFINITY, -INFINITY);

#pragma unroll  // full unroll: weight s_loads CSE'd across k, gathers hoisted
  for (int kk = 0; kk < 5; ++kk) {
    // & 2047: insurance — a bad index becomes a wrong answer, not an abort.
    const int nb = knn[p * KNBR + kq * 5 + kk] & 2047;
    const float* __restrict__ yp = ybase + (size_t)nb * 64;

    float h1[32];
#pragma unroll
    for (int o = 0; o < 32; o += 4) {
      const float4 v = *(const float4*)(yp + o);
      h1[o] = t1c[o] + v.x;
      h1[o + 1] = t1c[o + 1] + v.y;
      h1[o + 2] = t1c[o + 2] + v.z;
      h1[o + 3] = t1c[o + 3] + v.w;
    }
#pragma unroll
    for (int o = 0; o < 32; ++o) h1[o] = fmaxf(h1[o], 0.2f * h1[o]);

    // layer 2 (full 32 outputs, paired)
    float2 a2[16];
#pragma unroll
    for (int o2 = 0; o2 < 16; ++o2) a2[o2] = *(const float2*)(B2F + 2 * o2);
#pragma unroll
    for (int c = 0; c < 32; ++c) {
      const float hc = h1[c];
#pragma unroll
      for (int o2 = 0; o2 < 16; ++o2) {
        const float2 w = *(const float2*)(W2P + ((((o2 << 5) + c)) << 1));
        a2[o2].x = fmaf(w.x, hc, a2[o2].x);
        a2[o2].y = fmaf(w.y, hc, a2[o2].y);
      }
    }
    float h2[32];
#pragma unroll
    for (int o2 = 0; o2 < 16; ++o2) {
      h2[2 * o2] = fmaxf(a2[o2].x, 0.2f * a2[o2].x);
      h2[2 * o2 + 1] = fmaxf(a2[o2].y, 0.2f * a2[o2].y);
    }

    // layer 3 (this thread's 32-of-64 outputs, paired) + running max
    float2 c2[16];
#pragma unroll
    for (int j = 0; j < 16; ++j) c2[j] = make_float2(0.f, 0.f);
#pragma unroll
    for (int c = 0; c < 32; ++c) {
      const float hc = h2[c];
#pragma unroll
      for (int j = 0; j < 16; ++j) {
        const float2 w = *(const float2*)(W3P + (((((oh << 4) + j) << 5) + c) << 1));
        c2[j].x = fmaf(w.x, hc, c2[j].x);
        c2[j].y = fmaf(w.y, hc, c2[j].y);
      }
    }
#pragma unroll
    for (int j = 0; j < 16; ++j) {
      hm2[j].x = fmaxf(hm2[j].x, c2[j].x);
      hm2[j].y = fmaxf(hm2[j].y, c2[j].y);
    }
  }
  // reduce over the 4 k-quarters (lane bits 1-2); bit 0 (oh) preserved.
#pragma unroll
  for (int j = 0; j < 16; ++j) {
    hm2[j].x = fmaxf(hm2[j].x, __shfl_xor(hm2[j].x, 2));
    hm2[j].y = fmaxf(hm2[j].y, __shfl_xor(hm2[j].y, 2));
    hm2[j].x = fmaxf(hm2[j].x, __shfl_xor(hm2[j].x, 4));
    hm2[j].y = fmaxf(hm2[j].y, __shfl_xor(hm2[j].y, 4));
  }
  if (kq == 0) {
    // channel f = oh*32 + 2j (+1): u = f>>5 = oh, cc = f&31 = 2j (+1)
    float* op = out + (size_t)b * (32 * 4096) + 2 * n + oh;
#pragma unroll
    for (int j = 0; j < 16; ++j) {
      op[(2 * j) * 4096] = hm2[j].x;
      op[(2 * j + 1) * 4096] = hm2[j].y;
    }
  }
}

extern "C" void kernel_launch(void* const* d_in, const int* in_sizes, int n_in,
                              void* d_out, int out_size, void* d_ws, size_t ws_size,
                              hipStream_t stream) {
  const float* xyz = (const float*)d_in[0];
  const float* xyz_f = (const float*)d_in[1];
  const float* W1 = (const float*)d_in[2];
  const float* g1 = (const float*)d_in[3];
  const float* b1 = (const float*)d_in[4];
  const float* m1 = (const float*)d_in[5];
  const float* v1 = (const float*)d_in[6];
  const float* W2 = (const float*)d_in[7];
  const float* g2 = (const float*)d_in[8];
  const float* b2 = (const float*)d_in[9];
  const float* m2 = (const float*)d_in[10];
  const float* v2 = (const float*)d_in[11];
  const float* W3 = (const float*)d_in[12];
  float* ws = (float*)d_ws;
  float* out = (float*)d_out;
  int* knn = (int*)(ws + OFF_IDX);

  fold_kernel<<<1, 64, 0, stream>>>(W1, g1, b1, m1, v1, W2, g2, b2, m2, v2, W3,
                                    ws + OFF_W1AF, ws + OFF_W1BF, ws + OFF_B1F,
                                    ws + OFF_B2F, ws + OFF_W2P, ws + OFF_W3P);
  pre_kernel<<<128, 256, 0, stream>>>(xyz_f, ws + OFF_W1AF, ws + OFF_W1BF, ws + OFF_B1F,
                                      ws + OFF_YT);
  knn_kernel<<<512, 512, 0, stream>>>(xyz, knn);
  mlp_kernel<<<1024, 256, 0, stream>>>(ws, knn, out);
}